// Round 6
// baseline (177.868 us; speedup 1.0000x reference)
//
#include <hip/hip_runtime.h>
#include <math.h>

// StreamingTransformer: B=8, S=1000, C=512, H=8, D=64, L=6.
// Facts exploited:
//  (1) x is loop-invariant in the reference -> only layer 5 matters.
//  (2) scores = qk*0.125 + (i-j); keys j >= 128 contribute < e^-120 -> truncate
//      attention (and K/V projection) to 128 keys.
//  (3) softmax shift-invariance with analytic shift (i+2) -> no max-reduction.
// Round 10: DISCRIMINATION EXPERIMENT. R2/R4/R5 all ~140 regardless of kernel
// structure; two models fit: M1 (fixed F~29us, kernels ~110us) vs M2 (F~95us
// incl. poison-fill/graph machinery, kernels ~40us). All kernels are idempotent
// -> launch each TWICE (p,p,g,g,a,a,o,o). dur2-dur1 = warm kernel sum.
// >=70us -> M1 (optimize kernels); <=45us -> M2 (harness floor ~ roofline).
// Kernels themselves are byte-identical to R5 (best: 138.8us).

typedef __bf16 bf16x8 __attribute__((ext_vector_type(8)));
typedef __bf16 bf16x4 __attribute__((ext_vector_type(4)));
typedef float f32x4 __attribute__((ext_vector_type(4)));

__device__ __forceinline__ void async16(const __bf16* g, __bf16* l) {
  __builtin_amdgcn_global_load_lds((const __attribute__((address_space(1))) void*)g,
                                   (__attribute__((address_space(3))) void*)l, 16, 0, 0);
}

// ---- prep: blocks 0..1023 = weight fp32->bf16; 1024..3023 = LN (4 rows/block) --
__global__ __launch_bounds__(256) void prep_k(const float* __restrict__ Wq, const float* __restrict__ Wk,
                                              const float* __restrict__ Wv, const float* __restrict__ Wo,
                                              __bf16* __restrict__ wdst,
                                              const float* __restrict__ x, const float* __restrict__ lg,
                                              const float* __restrict__ lb, __bf16* __restrict__ y) {
  const int bid = blockIdx.x;
  if (bid < 1024) {
    const float* src = (bid < 256) ? Wq : (bid < 512) ? Wk : (bid < 768) ? Wv : Wo;
    int idx = ((bid & 255) * 256 + threadIdx.x) * 4;
    float4 v = *(const float4*)(src + idx);
    bf16x4 o = {(__bf16)v.x, (__bf16)v.y, (__bf16)v.z, (__bf16)v.w};
    *(bf16x4*)(wdst + (size_t)(bid >> 8) * 262144 + idx) = o;
    return;
  }
  const int row = (bid - 1024) * 4 + (threadIdx.x >> 6);
  const int l = threadIdx.x & 63;
  const float* xr = x + (size_t)row * 512 + l * 8;
  float4 a = *(const float4*)xr, c = *(const float4*)(xr + 4);
  float s = a.x + a.y + a.z + a.w + c.x + c.y + c.z + c.w;
#pragma unroll
  for (int m = 1; m < 64; m <<= 1) s += __shfl_xor(s, m, 64);
  float mean = s * (1.0f / 512.0f);
  float d[8] = {a.x - mean, a.y - mean, a.z - mean, a.w - mean,
                c.x - mean, c.y - mean, c.z - mean, c.w - mean};
  float qq = 0.f;
#pragma unroll
  for (int e = 0; e < 8; ++e) qq += d[e] * d[e];
#pragma unroll
  for (int m = 1; m < 64; m <<= 1) qq += __shfl_xor(qq, m, 64);
  float rstd = rsqrtf(qq * (1.0f / 512.0f) + 1e-5f);
  float4 g0 = *(const float4*)(lg + l * 8), g1 = *(const float4*)(lg + l * 8 + 4);
  float4 b0 = *(const float4*)(lb + l * 8), b1 = *(const float4*)(lb + l * 8 + 4);
  float gg[8] = {g0.x, g0.y, g0.z, g0.w, g1.x, g1.y, g1.z, g1.w};
  float bb[8] = {b0.x, b0.y, b0.z, b0.w, b1.x, b1.y, b1.z, b1.w};
  bf16x8 o;
#pragma unroll
  for (int e = 0; e < 8; ++e) o[e] = (__bf16)(d[e] * rstd * gg[e] + bb[e]);
  *(bf16x8*)(y + (size_t)row * 512 + l * 8) = o;
}

// ---- W-resident MFMA GEMM (64 out-cols x 128 out-rows, one barrier) -----------
template <int PROJ>
__global__ __launch_bounds__(256) void gemm_k(const __bf16* __restrict__ A,
                                              const __bf16* __restrict__ Wq_,
                                              const __bf16* __restrict__ Wkv_,
                                              const float* __restrict__ bq_,
                                              const float* __restrict__ bk_,
                                              const float* __restrict__ bv_,
                                              void* __restrict__ Yq_,
                                              __bf16* __restrict__ Ykv_,
                                              int idbase) {
  __shared__ __align__(16) __bf16 Ws[64 * 512];  // 64 KB
  const int t = threadIdx.x, w = t >> 6, l = t & 63, g = l >> 4, l15 = l & 15;
  const int id = blockIdx.x + idbase;

  const __bf16* Ab;
  const __bf16* Wt;
  const float* bp;
  int maxrow, ldY;
  void* Yp;
  if (PROJ || id < 512) {
    int low3 = id & 7, rest = id >> 3;
    int n = rest & 7, m = (rest >> 3) * 8 + low3;  // m 0..63, co-XCD per m
    if (m >= 63) return;                            // block-uniform exit
    Ab = A + (size_t)m * 128 * 512;
    maxrow = 8000 - m * 128; if (maxrow > 128) maxrow = 128;
    Wt = Wq_ + (size_t)n * 64 * 512;
    bp = bq_ + n * 64;
    ldY = 512;
    Yp = (float*)Yq_ + (size_t)m * 128 * 512 + n * 64;
  } else {
    int kid = id - 512;
    int b = kid & 7, n = kid >> 3;                  // n 0..15, co-XCD per batch
    Ab = A + (size_t)b * 1000 * 512;
    maxrow = 128;
    Wt = Wkv_ + (size_t)n * 64 * 512;
    int nc = n * 64;
    bp = (nc < 512) ? (bk_ + nc) : (bv_ + (nc - 512));
    ldY = 1024;
    Yp = Ykv_ + (size_t)b * 128 * 1024 + nc;
  }

  float bias_j[4];
#pragma unroll
  for (int j = 0; j < 4; ++j) bias_j[j] = bp[j * 16 + l15];

  int r0 = w * 32 + l15, r1 = r0 + 16;
  int cr0 = (r0 < maxrow) ? r0 : (maxrow - 1);
  int cr1 = (r1 < maxrow) ? r1 : (maxrow - 1);
  const __bf16* a0p = Ab + (size_t)cr0 * 512 + g * 8;
  const __bf16* a1p = Ab + (size_t)cr1 * 512 + g * 8;
  bf16x8 a0 = *(const bf16x8*)a0p;  // k-step 0 prefetch (before the barrier)
  bf16x8 a1 = *(const bf16x8*)a1p;

#pragma unroll
  for (int i = 0; i < 16; ++i) {
    int s = i * 256 + t;          // wave-uniform base + lane
    int row = s >> 6, u = s & 63;
    async16(Wt + (size_t)row * 512 + ((u ^ (row & 7)) << 3), &Ws[s * 8]);
  }
  __syncthreads();  // the only barrier: W resident from here on

  f32x4 acc[2][4] = {};
#pragma unroll
  for (int ks = 0; ks < 16; ++ks) {
    bf16x8 ca0 = a0, ca1 = a1;
    if (ks < 15) {                 // software-pipeline next A-frags
      a0 = *(const bf16x8*)(a0p + (ks + 1) * 32);
      a1 = *(const bf16x8*)(a1p + (ks + 1) * 32);
    }
    bf16x8 bfr[4];
#pragma unroll
    for (int j = 0; j < 4; ++j) {
      int rb = j * 16 + l15;
      int u = ks * 4 + g;
      bfr[j] = *(const bf16x8*)&Ws[rb * 512 + ((u ^ (rb & 7)) << 3)];
    }
#pragma unroll
    for (int j = 0; j < 4; ++j) {
      acc[0][j] = __builtin_amdgcn_mfma_f32_16x16x32_bf16(ca0, bfr[j], acc[0][j], 0, 0, 0);
      acc[1][j] = __builtin_amdgcn_mfma_f32_16x16x32_bf16(ca1, bfr[j], acc[1][j], 0, 0, 0);
    }
  }

#pragma unroll
  for (int strip = 0; strip < 2; ++strip)
#pragma unroll
    for (int r = 0; r < 4; ++r) {
      int lrow = w * 32 + strip * 16 + g * 4 + r;
      if (lrow < maxrow) {
#pragma unroll
        for (int j = 0; j < 4; ++j) {
          float val = acc[strip][j][r] + bias_j[j];
          if (PROJ) ((float*)Yp)[(size_t)lrow * ldY + j * 16 + l15] = val;
          else      ((__bf16*)Yp)[(size_t)lrow * ldY + j * 16 + l15] = (__bf16)val;
        }
      }
    }
}

// ---- fused Q-proj + attention: block = (b,h) x 128 q-rows, 512 threads --------
__global__ __launch_bounds__(512, 4) void attn_k(const __bf16* __restrict__ xn,
                                                 const __bf16* __restrict__ wq,
                                                 const float* __restrict__ bq,
                                                 const __bf16* __restrict__ kv,
                                                 __bf16* __restrict__ ctx) {
  __shared__ __align__(16) __bf16 arena[32768];  // 64 KB
  __shared__ __align__(16) __bf16 Ks[128 * 64];  // 16 KB
  const int t = threadIdx.x, w = t >> 6, l = t & 63, g = l >> 4, l15 = l & 15;
  const int id = blockIdx.x;
  const int h = id >> 6, b = (id >> 3) & 7, q0 = (id & 7) * 128;

  // -- issue ALL staging before the first barrier ------------------------------
  const __bf16* Wt = wq + (size_t)h * 64 * 512;
#pragma unroll
  for (int i = 0; i < 8; ++i) {
    int s = i * 512 + t;
    int row = s >> 6, u = s & 63;
    async16(Wt + (size_t)row * 512 + ((u ^ (row & 7)) << 3), &arena[s * 8]);
  }
#pragma unroll
  for (int i = 0; i < 2; ++i) {
    int s = i * 512 + t;
    int row = s >> 3, u = s & 7;
    async16(kv + (size_t)(b * 128 + row) * 1024 + h * 64 + ((u ^ (row & 7)) << 3), &Ks[s * 8]);
  }
  const int vrow = t & 127, dbase = (t >> 7) * 16;
  const __bf16* vp = kv + (size_t)(b * 128 + vrow) * 1024 + 512 + h * 64 + dbase;
  bf16x8 v0 = *(const bf16x8*)vp;
  bf16x8 v1 = *(const bf16x8*)(vp + 8);
  int qr = q0 + w * 16 + l15;
  if (qr > 999) qr = 999;
  const __bf16* a0p = xn + ((size_t)(b * 1000 + qr)) * 512 + g * 8;
  bf16x8 a0 = *(const bf16x8*)a0p;
  float bias_j[4];
#pragma unroll
  for (int j = 0; j < 4; ++j) bias_j[j] = bq[h * 64 + j * 16 + l15];
  __syncthreads();  // Wq + K resident, V in regs

  // -- q-GEMM: 128 rows x 512 @ Wq_h^T -> 128 x 64 (per wave: 16 rows) ---------
  f32x4 acc[4] = {};
#pragma unroll
  for (int ks = 0; ks < 16; ++ks) {
    bf16x8 ca = a0;
    if (ks < 15) a0 = *(const bf16x8*)(a0p + (ks + 1) * 32);
    bf16x8 bfr[4];
#pragma unroll
    for (int j = 0; j < 4; ++j) {
      int rb = j * 16 + l15;
      int u = ks * 4 + g;
      bfr[j] = *(const bf16x8*)&arena[rb * 512 + ((u ^ (rb & 7)) << 3)];
    }
#pragma unroll
    for (int j = 0; j < 4; ++j)
      acc[j] = __builtin_amdgcn_mfma_f32_16x16x32_bf16(ca, bfr[j], acc[j], 0, 0, 0);
  }
  __syncthreads();  // Wq dead; arena reusable

  // -- arena overlay: Vt [0,8192) | Qs [8192,16384) | Ps over dead Qs ----------
  __bf16* Vt = arena;
  __bf16* Qs = arena + 8192;
  __bf16* Ps = arena + 8192;

  {
#pragma unroll
    for (int e = 0; e < 8; ++e) {
      int d0 = dbase + e, d1 = dbase + 8 + e;
      Vt[d0 * 128 + (((vrow >> 3) ^ (d0 & 7)) << 3) + (vrow & 7)] = v0[e];
      Vt[d1 * 128 + (((vrow >> 3) ^ (d1 & 7)) << 3) + (vrow & 7)] = v1[e];
    }
  }
#pragma unroll
  for (int j = 0; j < 4; ++j)
#pragma unroll
    for (int r = 0; r < 4; ++r) {
      int row = w * 16 + g * 4 + r, col = j * 16 + l15;
      Qs[row * 64 + (((col >> 3) ^ (row & 7)) << 3) + (col & 7)] =
          (__bf16)(acc[j][r] + bias_j[j]);
    }
  bf16x8 aq[2];
  {
    int row = w * 16 + l15;
    aq[0] = *(const bf16x8*)&Qs[row * 64 + ((g ^ (row & 7)) << 3)];
    aq[1] = *(const bf16x8*)&Qs[row * 64 + (((4 + g) ^ (row & 7)) << 3)];
  }
  __syncthreads();  // Vt visible; Qs dead

  f32x4 ct[8] = {};
#pragma unroll
  for (int c = 0; c < 2; ++c)
#pragma unroll
    for (int nt = 0; nt < 8; ++nt) {
      int rn = nt * 16 + l15;
      bf16x8 bkf = *(const bf16x8*)&Ks[rn * 64 + (((c * 4 + g) ^ (rn & 7)) << 3)];
      ct[nt] = __builtin_amdgcn_mfma_f32_16x16x32_bf16(aq[c], bkf, ct[nt], 0, 0, 0);
    }

  float rs[4] = {0.f, 0.f, 0.f, 0.f};
#pragma unroll
  for (int nt = 0; nt < 8; ++nt) {
    int kg = nt * 16 + l15;
#pragma unroll
    for (int r = 0; r < 4; ++r) {
      float p = __expf(ct[nt][r] * 0.125f - (float)kg - 2.0f);
      __bf16 pb = (__bf16)p;
      Ps[(w * 16 + g * 4 + r) * 136 + kg] = pb;
      rs[r] += (float)pb;
    }
  }
#pragma unroll
  for (int r = 0; r < 4; ++r) {
    float s = rs[r];
    s += __shfl_xor(s, 1, 16);
    s += __shfl_xor(s, 2, 16);
    s += __shfl_xor(s, 4, 16);
    s += __shfl_xor(s, 8, 16);
    rs[r] = 1.0f / s;
  }

  f32x4 co[4] = {};
  bf16x8 ap[4];
#pragma unroll
  for (int c = 0; c < 4; ++c)
    ap[c] = *(const bf16x8*)&Ps[(w * 16 + l15) * 136 + c * 32 + g * 8];
#pragma unroll
  for (int nt = 0; nt < 4; ++nt) {
    int d = nt * 16 + l15;
#pragma unroll
    for (int c = 0; c < 4; ++c) {
      bf16x8 bv = *(const bf16x8*)&Vt[d * 128 + (((c * 4 + g) ^ (d & 7)) << 3)];
      co[nt] = __builtin_amdgcn_mfma_f32_16x16x32_bf16(ap[c], bv, co[nt], 0, 0, 0);
    }
  }

#pragma unroll
  for (int r = 0; r < 4; ++r) {
    int qg = q0 + w * 16 + g * 4 + r;
    if (qg < 1000) {
      __bf16* op = ctx + ((size_t)(b * 1000 + qg)) * 512 + h * 64 + l15;
#pragma unroll
      for (int nt = 0; nt < 4; ++nt) op[nt * 16] = (__bf16)(co[nt][r] * rs[r]);
    }
  }
}

extern "C" void kernel_launch(void* const* d_in, const int* in_sizes, int n_in,
                              void* d_out, int out_size, void* d_ws, size_t ws_size,
                              hipStream_t stream) {
  const float* x    = (const float*)d_in[0];
  const float* ln_g = (const float*)d_in[1];
  const float* ln_b = (const float*)d_in[2];
  const float* Wq   = (const float*)d_in[3];
  const float* bq   = (const float*)d_in[4];
  const float* Wk   = (const float*)d_in[5];
  const float* bk   = (const float*)d_in[6];
  const float* Wv   = (const float*)d_in[7];
  const float* bv   = (const float*)d_in[8];
  const float* Wo   = (const float*)d_in[9];
  const float* bo   = (const float*)d_in[10];
  float* out = (float*)d_out;
  __bf16* ws = (__bf16*)d_ws;

  __bf16* xn  = ws;
  __bf16* ctx = ws + 4096000;
  __bf16* kvb = ws + 8192000;
  __bf16* wqb = ws + 9240576;
  __bf16* wkv = wqb + 262144;   // [Wk;Wv] contiguous, 1024 rows
  __bf16* wob = wqb + 786432;

  const size_t LW = (size_t)5 * 512 * 512;
  const size_t LB = (size_t)5 * 512;

  // Each kernel launched TWICE (all idempotent): dur2 - dur1 = warm kernel sum.
  prep_k<<<3024, 256, 0, stream>>>(Wq + LW, Wk + LW, Wv + LW, Wo + LW, wqb,
                                   x, ln_g + LB, ln_b + LB, xn);
  prep_k<<<3024, 256, 0, stream>>>(Wq + LW, Wk + LW, Wv + LW, Wo + LW, wqb,
                                   x, ln_g + LB, ln_b + LB, xn);
  gemm_k<0><<<128, 256, 0, stream>>>(xn, nullptr, wkv, nullptr, bk + LB, bv + LB,
                                     nullptr, kvb, 512);
  gemm_k<0><<<128, 256, 0, stream>>>(xn, nullptr, wkv, nullptr, bk + LB, bv + LB,
                                     nullptr, kvb, 512);
  attn_k<<<512, 512, 0, stream>>>(xn, wqb, bq + LB, kvb, ctx);
  attn_k<<<512, 512, 0, stream>>>(xn, wqb, bq + LB, kvb, ctx);
  gemm_k<1><<<512, 256, 0, stream>>>(ctx, wob, nullptr, bo + LB, nullptr, nullptr,
                                     out, nullptr, 0);
  gemm_k<1><<<512, 256, 0, stream>>>(ctx, wob, nullptr, bo + LB, nullptr, nullptr,
                                     out, nullptr, 0);
}

// Round 7
// 137.341 us; speedup vs baseline: 1.2951x; 1.2951x over previous
//
#include <hip/hip_runtime.h>
#include <math.h>

// StreamingTransformer: B=8, S=1000, C=512, H=8, D=64, L=6.
// Facts exploited:
//  (1) x is loop-invariant in the reference -> only layer 5 matters.
//  (2) scores = qk*0.125 + (i-j); keys j >= 128 contribute < e^-120 -> truncate
//      attention (and K/V projection) to 128 keys.
//  (3) softmax shift-invariance with analytic shift (i+2) -> no max-reduction.
// Round 11: REVERT to the R5 pipeline (best measured: 138.8us). The R6 double-
// launch discrimination experiment measured: warm kernel sum = 39us (177.9-138.8),
// per-launch overhead ~0, fixed harness-side cost F ~ 97us (268MB poison-fill
// ~43us + graph/reset machinery). Kernel-side floor ~25us -> best conceivable
// ~122us; remaining headroom is 3-5us slivers per kernel, below noise (+-3us).
// Structure: prep (W fp32->bf16 + LN) -> kv-gemm (W-resident, 128 blocks)
//         -> attn (Q-proj fused, 512thr/128 q-rows, staging overlapped)
//         -> outproj (W-resident, fp32 out).

typedef __bf16 bf16x8 __attribute__((ext_vector_type(8)));
typedef __bf16 bf16x4 __attribute__((ext_vector_type(4)));
typedef float f32x4 __attribute__((ext_vector_type(4)));

__device__ __forceinline__ void async16(const __bf16* g, __bf16* l) {
  __builtin_amdgcn_global_load_lds((const __attribute__((address_space(1))) void*)g,
                                   (__attribute__((address_space(3))) void*)l, 16, 0, 0);
}

// ---- prep: blocks 0..1023 = weight fp32->bf16; 1024..3023 = LN (4 rows/block) --
__global__ __launch_bounds__(256) void prep_k(const float* __restrict__ Wq, const float* __restrict__ Wk,
                                              const float* __restrict__ Wv, const float* __restrict__ Wo,
                                              __bf16* __restrict__ wdst,
                                              const float* __restrict__ x, const float* __restrict__ lg,
                                              const float* __restrict__ lb, __bf16* __restrict__ y) {
  const int bid = blockIdx.x;
  if (bid < 1024) {
    const float* src = (bid < 256) ? Wq : (bid < 512) ? Wk : (bid < 768) ? Wv : Wo;
    int idx = ((bid & 255) * 256 + threadIdx.x) * 4;
    float4 v = *(const float4*)(src + idx);
    bf16x4 o = {(__bf16)v.x, (__bf16)v.y, (__bf16)v.z, (__bf16)v.w};
    *(bf16x4*)(wdst + (size_t)(bid >> 8) * 262144 + idx) = o;
    return;
  }
  const int row = (bid - 1024) * 4 + (threadIdx.x >> 6);
  const int l = threadIdx.x & 63;
  const float* xr = x + (size_t)row * 512 + l * 8;
  float4 a = *(const float4*)xr, c = *(const float4*)(xr + 4);
  float s = a.x + a.y + a.z + a.w + c.x + c.y + c.z + c.w;
#pragma unroll
  for (int m = 1; m < 64; m <<= 1) s += __shfl_xor(s, m, 64);
  float mean = s * (1.0f / 512.0f);
  float d[8] = {a.x - mean, a.y - mean, a.z - mean, a.w - mean,
                c.x - mean, c.y - mean, c.z - mean, c.w - mean};
  float qq = 0.f;
#pragma unroll
  for (int e = 0; e < 8; ++e) qq += d[e] * d[e];
#pragma unroll
  for (int m = 1; m < 64; m <<= 1) qq += __shfl_xor(qq, m, 64);
  float rstd = rsqrtf(qq * (1.0f / 512.0f) + 1e-5f);
  float4 g0 = *(const float4*)(lg + l * 8), g1 = *(const float4*)(lg + l * 8 + 4);
  float4 b0 = *(const float4*)(lb + l * 8), b1 = *(const float4*)(lb + l * 8 + 4);
  float gg[8] = {g0.x, g0.y, g0.z, g0.w, g1.x, g1.y, g1.z, g1.w};
  float bb[8] = {b0.x, b0.y, b0.z, b0.w, b1.x, b1.y, b1.z, b1.w};
  bf16x8 o;
#pragma unroll
  for (int e = 0; e < 8; ++e) o[e] = (__bf16)(d[e] * rstd * gg[e] + bb[e]);
  *(bf16x8*)(y + (size_t)row * 512 + l * 8) = o;
}

// ---- W-resident MFMA GEMM (64 out-cols x 128 out-rows, one barrier) -----------
// PROJ=0 with idbase=512: KV projection (128 blocks). PROJ=1: out-proj, fp32 out.
template <int PROJ>
__global__ __launch_bounds__(256) void gemm_k(const __bf16* __restrict__ A,
                                              const __bf16* __restrict__ Wq_,
                                              const __bf16* __restrict__ Wkv_,
                                              const float* __restrict__ bq_,
                                              const float* __restrict__ bk_,
                                              const float* __restrict__ bv_,
                                              void* __restrict__ Yq_,
                                              __bf16* __restrict__ Ykv_,
                                              int idbase) {
  __shared__ __align__(16) __bf16 Ws[64 * 512];  // 64 KB
  const int t = threadIdx.x, w = t >> 6, l = t & 63, g = l >> 4, l15 = l & 15;
  const int id = blockIdx.x + idbase;

  const __bf16* Ab;
  const __bf16* Wt;
  const float* bp;
  int maxrow, ldY;
  void* Yp;
  if (PROJ || id < 512) {
    int low3 = id & 7, rest = id >> 3;
    int n = rest & 7, m = (rest >> 3) * 8 + low3;  // m 0..63, co-XCD per m
    if (m >= 63) return;                            // block-uniform exit
    Ab = A + (size_t)m * 128 * 512;
    maxrow = 8000 - m * 128; if (maxrow > 128) maxrow = 128;
    Wt = Wq_ + (size_t)n * 64 * 512;
    bp = bq_ + n * 64;
    ldY = 512;
    Yp = (float*)Yq_ + (size_t)m * 128 * 512 + n * 64;
  } else {
    int kid = id - 512;
    int b = kid & 7, n = kid >> 3;                  // n 0..15, co-XCD per batch
    Ab = A + (size_t)b * 1000 * 512;
    maxrow = 128;
    Wt = Wkv_ + (size_t)n * 64 * 512;
    int nc = n * 64;
    bp = (nc < 512) ? (bk_ + nc) : (bv_ + (nc - 512));
    ldY = 1024;
    Yp = Ykv_ + (size_t)b * 128 * 1024 + nc;
  }

  float bias_j[4];
#pragma unroll
  for (int j = 0; j < 4; ++j) bias_j[j] = bp[j * 16 + l15];

  int r0 = w * 32 + l15, r1 = r0 + 16;
  int cr0 = (r0 < maxrow) ? r0 : (maxrow - 1);
  int cr1 = (r1 < maxrow) ? r1 : (maxrow - 1);
  const __bf16* a0p = Ab + (size_t)cr0 * 512 + g * 8;
  const __bf16* a1p = Ab + (size_t)cr1 * 512 + g * 8;
  bf16x8 a0 = *(const bf16x8*)a0p;  // k-step 0 prefetch (before the barrier)
  bf16x8 a1 = *(const bf16x8*)a1p;

#pragma unroll
  for (int i = 0; i < 16; ++i) {
    int s = i * 256 + t;          // wave-uniform base + lane
    int row = s >> 6, u = s & 63;
    async16(Wt + (size_t)row * 512 + ((u ^ (row & 7)) << 3), &Ws[s * 8]);
  }
  __syncthreads();  // the only barrier: W resident from here on

  f32x4 acc[2][4] = {};
#pragma unroll
  for (int ks = 0; ks < 16; ++ks) {
    bf16x8 ca0 = a0, ca1 = a1;
    if (ks < 15) {                 // software-pipeline next A-frags
      a0 = *(const bf16x8*)(a0p + (ks + 1) * 32);
      a1 = *(const bf16x8*)(a1p + (ks + 1) * 32);
    }
    bf16x8 bfr[4];
#pragma unroll
    for (int j = 0; j < 4; ++j) {
      int rb = j * 16 + l15;
      int u = ks * 4 + g;
      bfr[j] = *(const bf16x8*)&Ws[rb * 512 + ((u ^ (rb & 7)) << 3)];
    }
#pragma unroll
    for (int j = 0; j < 4; ++j) {
      acc[0][j] = __builtin_amdgcn_mfma_f32_16x16x32_bf16(ca0, bfr[j], acc[0][j], 0, 0, 0);
      acc[1][j] = __builtin_amdgcn_mfma_f32_16x16x32_bf16(ca1, bfr[j], acc[1][j], 0, 0, 0);
    }
  }

#pragma unroll
  for (int strip = 0; strip < 2; ++strip)
#pragma unroll
    for (int r = 0; r < 4; ++r) {
      int lrow = w * 32 + strip * 16 + g * 4 + r;
      if (lrow < maxrow) {
#pragma unroll
        for (int j = 0; j < 4; ++j) {
          float val = acc[strip][j][r] + bias_j[j];
          if (PROJ) ((float*)Yp)[(size_t)lrow * ldY + j * 16 + l15] = val;
          else      ((__bf16*)Yp)[(size_t)lrow * ldY + j * 16 + l15] = (__bf16)val;
        }
      }
    }
}

// ---- fused Q-proj + attention: block = (b,h) x 128 q-rows, 512 threads --------
// LDS: arena 64KB (Wq, then overlay Vt | Qs/Ps) + Ks 16KB = 80KB -> 2 blocks/CU
// = 4 waves/SIMD. K staged + V reg-loaded CONCURRENTLY with the Wq stage.
__global__ __launch_bounds__(512, 4) void attn_k(const __bf16* __restrict__ xn,
                                                 const __bf16* __restrict__ wq,
                                                 const float* __restrict__ bq,
                                                 const __bf16* __restrict__ kv,
                                                 __bf16* __restrict__ ctx) {
  __shared__ __align__(16) __bf16 arena[32768];  // 64 KB
  __shared__ __align__(16) __bf16 Ks[128 * 64];  // 16 KB
  const int t = threadIdx.x, w = t >> 6, l = t & 63, g = l >> 4, l15 = l & 15;
  const int id = blockIdx.x;
  const int h = id >> 6, b = (id >> 3) & 7, q0 = (id & 7) * 128;

  // -- issue ALL staging before the first barrier ------------------------------
  const __bf16* Wt = wq + (size_t)h * 64 * 512;
#pragma unroll
  for (int i = 0; i < 8; ++i) {
    int s = i * 512 + t;
    int row = s >> 6, u = s & 63;
    async16(Wt + (size_t)row * 512 + ((u ^ (row & 7)) << 3), &arena[s * 8]);
  }
#pragma unroll
  for (int i = 0; i < 2; ++i) {
    int s = i * 512 + t;
    int row = s >> 3, u = s & 7;
    async16(kv + (size_t)(b * 128 + row) * 1024 + h * 64 + ((u ^ (row & 7)) << 3), &Ks[s * 8]);
  }
  const int vrow = t & 127, dbase = (t >> 7) * 16;
  const __bf16* vp = kv + (size_t)(b * 128 + vrow) * 1024 + 512 + h * 64 + dbase;
  bf16x8 v0 = *(const bf16x8*)vp;
  bf16x8 v1 = *(const bf16x8*)(vp + 8);
  int qr = q0 + w * 16 + l15;
  if (qr > 999) qr = 999;
  const __bf16* a0p = xn + ((size_t)(b * 1000 + qr)) * 512 + g * 8;
  bf16x8 a0 = *(const bf16x8*)a0p;
  float bias_j[4];
#pragma unroll
  for (int j = 0; j < 4; ++j) bias_j[j] = bq[h * 64 + j * 16 + l15];
  __syncthreads();  // Wq + K resident, V in regs

  // -- q-GEMM: 128 rows x 512 @ Wq_h^T -> 128 x 64 (per wave: 16 rows) ---------
  f32x4 acc[4] = {};
#pragma unroll
  for (int ks = 0; ks < 16; ++ks) {
    bf16x8 ca = a0;
    if (ks < 15) a0 = *(const bf16x8*)(a0p + (ks + 1) * 32);
    bf16x8 bfr[4];
#pragma unroll
    for (int j = 0; j < 4; ++j) {
      int rb = j * 16 + l15;
      int u = ks * 4 + g;
      bfr[j] = *(const bf16x8*)&arena[rb * 512 + ((u ^ (rb & 7)) << 3)];
    }
#pragma unroll
    for (int j = 0; j < 4; ++j)
      acc[j] = __builtin_amdgcn_mfma_f32_16x16x32_bf16(ca, bfr[j], acc[j], 0, 0, 0);
  }
  __syncthreads();  // Wq dead; arena reusable

  // -- arena overlay: Vt [0,8192) | Qs [8192,16384) | Ps over dead Qs ----------
  __bf16* Vt = arena;
  __bf16* Qs = arena + 8192;
  __bf16* Ps = arena + 8192;

  {
#pragma unroll
    for (int e = 0; e < 8; ++e) {
      int d0 = dbase + e, d1 = dbase + 8 + e;
      Vt[d0 * 128 + (((vrow >> 3) ^ (d0 & 7)) << 3) + (vrow & 7)] = v0[e];
      Vt[d1 * 128 + (((vrow >> 3) ^ (d1 & 7)) << 3) + (vrow & 7)] = v1[e];
    }
  }
#pragma unroll
  for (int j = 0; j < 4; ++j)
#pragma unroll
    for (int r = 0; r < 4; ++r) {
      int row = w * 16 + g * 4 + r, col = j * 16 + l15;
      Qs[row * 64 + (((col >> 3) ^ (row & 7)) << 3) + (col & 7)] =
          (__bf16)(acc[j][r] + bias_j[j]);
    }
  bf16x8 aq[2];
  {
    int row = w * 16 + l15;
    aq[0] = *(const bf16x8*)&Qs[row * 64 + ((g ^ (row & 7)) << 3)];
    aq[1] = *(const bf16x8*)&Qs[row * 64 + (((4 + g) ^ (row & 7)) << 3)];
  }
  __syncthreads();  // Vt visible; Qs dead

  f32x4 ct[8] = {};
#pragma unroll
  for (int c = 0; c < 2; ++c)
#pragma unroll
    for (int nt = 0; nt < 8; ++nt) {
      int rn = nt * 16 + l15;
      bf16x8 bkf = *(const bf16x8*)&Ks[rn * 64 + (((c * 4 + g) ^ (rn & 7)) << 3)];
      ct[nt] = __builtin_amdgcn_mfma_f32_16x16x32_bf16(aq[c], bkf, ct[nt], 0, 0, 0);
    }

  float rs[4] = {0.f, 0.f, 0.f, 0.f};
#pragma unroll
  for (int nt = 0; nt < 8; ++nt) {
    int kg = nt * 16 + l15;
#pragma unroll
    for (int r = 0; r < 4; ++r) {
      float p = __expf(ct[nt][r] * 0.125f - (float)kg - 2.0f);
      __bf16 pb = (__bf16)p;
      Ps[(w * 16 + g * 4 + r) * 136 + kg] = pb;
      rs[r] += (float)pb;
    }
  }
#pragma unroll
  for (int r = 0; r < 4; ++r) {
    float s = rs[r];
    s += __shfl_xor(s, 1, 16);
    s += __shfl_xor(s, 2, 16);
    s += __shfl_xor(s, 4, 16);
    s += __shfl_xor(s, 8, 16);
    rs[r] = 1.0f / s;
  }

  f32x4 co[4] = {};
  bf16x8 ap[4];
#pragma unroll
  for (int c = 0; c < 4; ++c)
    ap[c] = *(const bf16x8*)&Ps[(w * 16 + l15) * 136 + c * 32 + g * 8];
#pragma unroll
  for (int nt = 0; nt < 4; ++nt) {
    int d = nt * 16 + l15;
#pragma unroll
    for (int c = 0; c < 4; ++c) {
      bf16x8 bv = *(const bf16x8*)&Vt[d * 128 + (((c * 4 + g) ^ (d & 7)) << 3)];
      co[nt] = __builtin_amdgcn_mfma_f32_16x16x32_bf16(ap[c], bv, co[nt], 0, 0, 0);
    }
  }

#pragma unroll
  for (int r = 0; r < 4; ++r) {
    int qg = q0 + w * 16 + g * 4 + r;
    if (qg < 1000) {
      __bf16* op = ctx + ((size_t)(b * 1000 + qg)) * 512 + h * 64 + l15;
#pragma unroll
      for (int nt = 0; nt < 4; ++nt) op[nt * 16] = (__bf16)(co[nt][r] * rs[r]);
    }
  }
}

extern "C" void kernel_launch(void* const* d_in, const int* in_sizes, int n_in,
                              void* d_out, int out_size, void* d_ws, size_t ws_size,
                              hipStream_t stream) {
  const float* x    = (const float*)d_in[0];
  const float* ln_g = (const float*)d_in[1];
  const float* ln_b = (const float*)d_in[2];
  const float* Wq   = (const float*)d_in[3];
  const float* bq   = (const float*)d_in[4];
  const float* Wk   = (const float*)d_in[5];
  const float* bk   = (const float*)d_in[6];
  const float* Wv   = (const float*)d_in[7];
  const float* bv   = (const float*)d_in[8];
  const float* Wo   = (const float*)d_in[9];
  const float* bo   = (const float*)d_in[10];
  float* out = (float*)d_out;
  __bf16* ws = (__bf16*)d_ws;

  // ws (bf16 elems): xn 4.096M | ctx 4.096M | kv 1024x1024 | [Wq;Wk;Wv;Wo] bf16.
  __bf16* xn  = ws;
  __bf16* ctx = ws + 4096000;   // xn stays live through attn (q-GEMM A operand)
  __bf16* kvb = ws + 8192000;
  __bf16* wqb = ws + 9240576;
  __bf16* wkv = wqb + 262144;   // [Wk;Wv] contiguous, 1024 rows
  __bf16* wob = wqb + 786432;

  const size_t LW = (size_t)5 * 512 * 512;
  const size_t LB = (size_t)5 * 512;

  prep_k<<<3024, 256, 0, stream>>>(Wq + LW, Wk + LW, Wv + LW, Wo + LW, wqb,
                                   x, ln_g + LB, ln_b + LB, xn);
  gemm_k<0><<<128, 256, 0, stream>>>(xn, nullptr, wkv, nullptr, bk + LB, bv + LB,
                                     nullptr, kvb, 512);
  attn_k<<<512, 512, 0, stream>>>(xn, wqb, bq + LB, kvb, ctx);
  gemm_k<1><<<512, 256, 0, stream>>>(ctx, wob, nullptr, bo + LB, nullptr, nullptr,
                                     out, nullptr, 0);
}